// Round 5
// baseline (866.834 us; speedup 1.0000x reference)
//
#include <hip/hip_runtime.h>

// FeatureEnhance: 4-stream PAM + CAM + shared 3x3 conv.
// S=4, B=2, C=256, CQ=32, H=W=64, N=HW=4096.
// Round 5: flash occupancy restructure (64q/64kv, 512 blocks, 2/CU);
// all large GEMMs (QK-proj, V-proj, CAM, conv) on MFMA via unified mm_k;
// GRAM stays f32 split-K for precision.

#define HW 4096

typedef unsigned short u16;
typedef __attribute__((ext_vector_type(4))) float f32x4;
typedef __attribute__((ext_vector_type(8))) short bf16x8;
typedef __attribute__((ext_vector_type(8))) unsigned short u16x8;
typedef __attribute__((ext_vector_type(4))) unsigned short u16x4;

__device__ __forceinline__ float bf2f(u16 u) { return __uint_as_float(((unsigned)u) << 16); }
__device__ __forceinline__ u16 f2bf(float f) {
    unsigned x = __float_as_uint(f);
    return (u16)((x + 0x7fffu + ((x >> 16) & 1u)) >> 16);
}
__device__ __forceinline__ void gload16(const void* g, void* l) {
    __builtin_amdgcn_global_load_lds((const __attribute__((address_space(1))) void*)g,
                                     (__attribute__((address_space(3))) void*)l, 16, 0, 0);
}

struct XPtrs { const float* p[4]; };

// ================= unified MFMA GEMM: C[m,n] = sum_k A[m,k] * BT[n,k] =================
// A bf16 row-major (lda), BT bf16 row-major (ldb). BM=128, BK=32, 4 waves.
enum { MM_QK = 0, MM_V = 1, MM_CAM = 2, MM_CONV = 3 };

template<int MODE>
__global__ __launch_bounds__(256)
void mm_k(const u16* __restrict__ A, const u16* __restrict__ BT,
          void* __restrict__ Cp,
          const float* __restrict__ b0, const float* __restrict__ b1,
          const float* __restrict__ gscale, XPtrs xs,
          int K, int lda, int ldb,
          long aBatch, long bBatch, long cBatch, int sb0)
{
    constexpr int BN = (MODE == MM_QK) ? 64 : 128;
    constexpr int NI = (MODE == MM_QK) ? 2 : 4;
    const int n0 = blockIdx.x * BN, m0 = blockIdx.y * 128, z = blockIdx.z;

    const u16* Ab = A + (MODE == MM_CAM ? (size_t)(z & 1) * aBatch : (size_t)z * aBatch)
                      + (size_t)m0 * lda;
    const u16* Bb = BT + (size_t)z * bBatch + (size_t)n0 * ldb;

    __shared__ u16 As[4096];                 // [kh][128 m][8]
    __shared__ u16 Bs[BN * 32];              // [kh][BN n][8]

    const int t = threadIdx.x, lane = t & 63, w = t >> 6;
    const int l15 = lane & 15, l4 = lane >> 4;
    const int mw = (w >> 1) * 64;
    const int nw = (w & 1) * (BN / 2);

    f32x4 acc[4][NI] = {};

    for (int kb = 0; kb < K; kb += 32) {
        gload16(Ab + (size_t)lane * lda + kb + w * 8,        &As[w * 1024]);
        gload16(Ab + (size_t)(64 + lane) * lda + kb + w * 8, &As[w * 1024 + 512]);
        if constexpr (MODE == MM_QK) {
            gload16(Bb + (size_t)lane * ldb + kb + w * 8, &Bs[w * 512]);
        } else {
            gload16(Bb + (size_t)lane * ldb + kb + w * 8,        &Bs[w * 1024]);
            gload16(Bb + (size_t)(64 + lane) * ldb + kb + w * 8, &Bs[w * 1024 + 512]);
        }
        __syncthreads();

        bf16x8 af[4], bf[NI];
        #pragma unroll
        for (int i = 0; i < 4; ++i)
            af[i] = *(const bf16x8*)&As[l4 * 1024 + (mw + i * 16 + l15) * 8];
        #pragma unroll
        for (int i = 0; i < NI; ++i)
            bf[i] = *(const bf16x8*)&Bs[l4 * (BN * 8) + (nw + i * 16 + l15) * 8];

        #pragma unroll
        for (int mi = 0; mi < 4; ++mi)
            #pragma unroll
            for (int ni = 0; ni < NI; ++ni)
                acc[mi][ni] = __builtin_amdgcn_mfma_f32_16x16x32_bf16(af[mi], bf[ni], acc[mi][ni], 0, 0, 0);
        __syncthreads();
    }

    #pragma unroll
    for (int mi = 0; mi < 4; ++mi) {
        #pragma unroll
        for (int ni = 0; ni < NI; ++ni) {
            #pragma unroll
            for (int r = 0; r < 4; ++r) {
                const int row = m0 + mw + mi * 16 + l4 * 4 + r;
                const int col = n0 + nw + ni * 16 + l15;
                float v = acc[mi][ni][r];
                if constexpr (MODE == MM_QK) {
                    v += (col < 32) ? b0[col] : b1[col - 32];
                    ((u16*)Cp)[(size_t)z * cBatch + (size_t)row * 64 + col] = f2bf(v);
                } else if constexpr (MODE == MM_V) {
                    v += b0[row];
                    ((u16*)Cp)[(size_t)z * cBatch + (size_t)row * HW + col] = f2bf(v);
                } else if constexpr (MODE == MM_CAM) {
                    const float* xb = xs.p[z >> 1] + (size_t)(z & 1) * (256 * HW);
                    v = gscale[0] * v + 5.f * xb[(size_t)row * HW + col];
                    ((float*)Cp)[(size_t)z * cBatch + (size_t)row * HW + col] = v;
                } else { // MM_CONV
                    v += b0[row];
                    ((float*)Cp)[(size_t)(sb0 + z) * cBatch + (size_t)row * HW + col] = v;
                }
            }
        }
    }
}

// ================= fused flash PAM =================
// QK: [sb][4096][64] bf16 (cols 0-31 Q, 32-63 K). Vh: [sb][256][4096] bf16.
// Yt: [sb][4096][256] f32 = gp * softmax(Q K^T) @ V^T.
// 8 waves: qg = w&1 (32 q-rows), ch = w>>1 (64 channels). ch==0 waves do softmax.
__global__ __launch_bounds__(512, 4)
void flash_k(const u16* __restrict__ QK, const u16* __restrict__ Vh,
             float* __restrict__ Yt, const float* __restrict__ gscale)
{
    __shared__ u16 Vs[256 * 64];     // 32KB: [c][slot ^ (c&7)][8]
    __shared__ u16 Ps[2][32 * 64];   // 8KB:  [qg][qrow][slot ^ (qrow&7)][8]
    __shared__ float Sc[2][32];

    const int sb = blockIdx.y;
    const int t = threadIdx.x, w = t >> 6, lane = t & 63;
    const int l15 = lane & 15, l4 = lane >> 4;
    const int qg = w & 1, ch = w >> 1;
    const int q0 = blockIdx.x * 64 + qg * 32;
    const int c0 = ch * 64;
    const bool sWave = (ch == 0);

    const u16* QKb = QK + (size_t)sb * ((size_t)HW * 64);
    const u16* Vb  = Vh + (size_t)sb * ((size_t)256 * HW);
    float* Yb = Yt + (size_t)sb * ((size_t)HW * 256);

    bf16x8 aq[2];
    if (sWave) {
        aq[0] = *(const bf16x8*)&QKb[(size_t)(q0 + l15) * 64 + l4 * 8];
        aq[1] = *(const bf16x8*)&QKb[(size_t)(q0 + 16 + l15) * 64 + l4 * 8];
    }

    f32x4 acc[2][4] = {};
    float mrun[2][4], lrun[2][4];
    #pragma unroll
    for (int a = 0; a < 2; ++a)
        #pragma unroll
        for (int r = 0; r < 4; ++r) { mrun[a][r] = -3.0e38f; lrun[a][r] = 0.f; }

    const f32x4 zero4 = {0.f, 0.f, 0.f, 0.f};

    for (int it = 0; it < 64; ++it) {
        const int m0 = it * 64;

        // stage V tile [256][64] bf16 -> LDS (pre-swizzled source, linear dest)
        #pragma unroll
        for (int i = 0; i < 4; ++i) {
            const int chunk = i * 512 + w * 64 + lane;
            const int c = chunk >> 3, kc = chunk & 7;
            const int mo = kc ^ (c & 7);
            gload16(Vb + (size_t)c * HW + m0 + mo * 8, &Vs[(i * 512 + w * 64) * 8]);
        }

        if (sWave) {
            #pragma unroll
            for (int qt = 0; qt < 2; ++qt) {
                f32x4 s[4];
                #pragma unroll
                for (int j = 0; j < 4; ++j) {
                    const bf16x8 bk = *(const bf16x8*)&QKb[(size_t)(m0 + j * 16 + l15) * 64 + 32 + l4 * 8];
                    s[j] = __builtin_amdgcn_mfma_f32_16x16x32_bf16(aq[qt], bk, zero4, 0, 0, 0);
                }
                #pragma unroll
                for (int r = 0; r < 4; ++r) {
                    float tmax = fmaxf(fmaxf(s[0][r], s[1][r]), fmaxf(s[2][r], s[3][r]));
                    tmax = fmaxf(tmax, __shfl_xor(tmax, 1));
                    tmax = fmaxf(tmax, __shfl_xor(tmax, 2));
                    tmax = fmaxf(tmax, __shfl_xor(tmax, 4));
                    tmax = fmaxf(tmax, __shfl_xor(tmax, 8));
                    const float mnew = fmaxf(mrun[qt][r], tmax);
                    const float scl = __expf(mrun[qt][r] - mnew);
                    mrun[qt][r] = mnew;
                    const int qrow = qt * 16 + l4 * 4 + r;
                    float tsum = 0.f;
                    #pragma unroll
                    for (int j = 0; j < 4; ++j) {
                        const float p = __expf(s[j][r] - mnew);
                        tsum += p;
                        const int sl = (j * 2 + (l15 >> 3)) ^ (qrow & 7);
                        Ps[qg][qrow * 64 + sl * 8 + (l15 & 7)] = f2bf(p);
                    }
                    tsum += __shfl_xor(tsum, 1);
                    tsum += __shfl_xor(tsum, 2);
                    tsum += __shfl_xor(tsum, 4);
                    tsum += __shfl_xor(tsum, 8);
                    lrun[qt][r] = lrun[qt][r] * scl + tsum;
                    if (l15 == 0) Sc[qg][qrow] = scl;
                    #pragma unroll
                    for (int ct = 0; ct < 4; ++ct) acc[qt][ct][r] *= scl;
                }
            }
        }
        __syncthreads();   // V staged; Ps + Sc visible

        if (!sWave) {
            #pragma unroll
            for (int qt = 0; qt < 2; ++qt)
                #pragma unroll
                for (int r = 0; r < 4; ++r) {
                    const float scl = Sc[qg][qt * 16 + l4 * 4 + r];
                    #pragma unroll
                    for (int ct = 0; ct < 4; ++ct) acc[qt][ct][r] *= scl;
                }
        }

        #pragma unroll
        for (int ks = 0; ks < 2; ++ks) {
            bf16x8 ap[2];
            #pragma unroll
            for (int qt = 0; qt < 2; ++qt) {
                const int qr = qt * 16 + l15;
                ap[qt] = *(const bf16x8*)&Ps[qg][qr * 64 + (((ks * 4 + l4) ^ (qr & 7)) << 3)];
            }
            #pragma unroll
            for (int ct = 0; ct < 4; ++ct) {
                const int c = c0 + ct * 16 + l15;
                const bf16x8 bv = *(const bf16x8*)&Vs[c * 64 + (((ks * 4 + l4) ^ (c & 7)) << 3)];
                acc[0][ct] = __builtin_amdgcn_mfma_f32_16x16x32_bf16(ap[0], bv, acc[0][ct], 0, 0, 0);
                acc[1][ct] = __builtin_amdgcn_mfma_f32_16x16x32_bf16(ap[1], bv, acc[1][ct], 0, 0, 0);
            }
        }
        __syncthreads();   // done reading Vs/Ps
    }

    if (sWave && l15 == 0) {
        #pragma unroll
        for (int qt = 0; qt < 2; ++qt)
            #pragma unroll
            for (int r = 0; r < 4; ++r)
                Sc[qg][qt * 16 + l4 * 4 + r] = 1.0f / lrun[qt][r];
    }
    __syncthreads();
    const float gp = gscale[0];
    #pragma unroll
    for (int qt = 0; qt < 2; ++qt) {
        #pragma unroll
        for (int r = 0; r < 4; ++r) {
            const float linv = Sc[qg][qt * 16 + l4 * 4 + r];
            const int row = q0 + qt * 16 + l4 * 4 + r;
            #pragma unroll
            for (int ct = 0; ct < 4; ++ct)
                Yb[(size_t)row * 256 + c0 + ct * 16 + l15] = gp * acc[qt][ct][r] * linv;
        }
    }
}

// ================= prep: X f32 [sb][256][4096] -> Xt bf16 [sb][4096][256] =================
__global__ __launch_bounds__(256)
void prep_k(XPtrs xs, u16* __restrict__ Xt)
{
    __shared__ float tile[64][65];
    const int sb = blockIdx.z;
    const int n0 = blockIdx.x * 64, c0 = blockIdx.y * 64;
    const float* X = xs.p[sb >> 1] + (size_t)(sb & 1) * (256 * HW);
    u16* Xo = Xt + (size_t)sb * ((size_t)HW * 256);
    const int t = threadIdx.x;
    {
        const int c = t >> 2, p = t & 3;
        const float4* s4 = (const float4*)&X[(size_t)(c0 + c) * HW + n0 + p * 16];
        #pragma unroll
        for (int i = 0; i < 4; ++i) {
            const float4 v = s4[i];
            tile[c][p * 16 + i * 4 + 0] = v.x;
            tile[c][p * 16 + i * 4 + 1] = v.y;
            tile[c][p * 16 + i * 4 + 2] = v.z;
            tile[c][p * 16 + i * 4 + 3] = v.w;
        }
    }
    __syncthreads();
    const int n = t >> 2, p = t & 3;
    u16 o[16];
    #pragma unroll
    for (int j = 0; j < 16; ++j) o[j] = f2bf(tile[p * 16 + j][n]);
    *(u16x8*)&Xo[(size_t)(n0 + n) * 256 + c0 + p * 16]     = *(u16x8*)&o[0];
    *(u16x8*)&Xo[(size_t)(n0 + n) * 256 + c0 + p * 16 + 8] = *(u16x8*)&o[8];
}

// ================= f32 split-K GRAM (precision-critical) =================
__global__ __launch_bounds__(256)
void gram_k(float* __restrict__ Gp, XPtrs xs)
{
    const int bx = blockIdx.x, by = blockIdx.y, bz = blockIdx.z;
    const int sbi = bz & 7;
    const int n0 = bx * 64, m0 = by * 64;
    const int t = threadIdx.x;
    const int tm = t >> 4, tn = t & 15;
    const float* xb = xs.p[sbi >> 1] + (size_t)(sbi & 1) * (256 * HW) + (bz >> 3) * 512;

    __shared__ float As[16][68];
    __shared__ float Bs[16][68];
    float acc[4][4] = {};

    for (int kb = 0; kb < 512; kb += 16) {
        {
            const int m = t >> 2, k0 = (t & 3) * 4;
            float4 v = *(const float4*)(xb + (size_t)(m0 + m) * HW + (kb + k0));
            As[k0 + 0][m] = v.x; As[k0 + 1][m] = v.y; As[k0 + 2][m] = v.z; As[k0 + 3][m] = v.w;
        }
        {
            const int n = t >> 2, k0 = (t & 3) * 4;
            float4 v = *(const float4*)(xb + (size_t)(n0 + n) * HW + (kb + k0));
            Bs[k0 + 0][n] = v.x; Bs[k0 + 1][n] = v.y; Bs[k0 + 2][n] = v.z; Bs[k0 + 3][n] = v.w;
        }
        __syncthreads();
        #pragma unroll
        for (int k = 0; k < 16; ++k) {
            const float4 a = *(const float4*)&As[k][tm * 4];
            const float4 b = *(const float4*)&Bs[k][tn * 4];
            acc[0][0] += a.x * b.x; acc[0][1] += a.x * b.y; acc[0][2] += a.x * b.z; acc[0][3] += a.x * b.w;
            acc[1][0] += a.y * b.x; acc[1][1] += a.y * b.y; acc[1][2] += a.y * b.z; acc[1][3] += a.y * b.w;
            acc[2][0] += a.z * b.x; acc[2][1] += a.z * b.y; acc[2][2] += a.z * b.z; acc[2][3] += a.z * b.w;
            acc[3][0] += a.w * b.x; acc[3][1] += a.w * b.y; acc[3][2] += a.w * b.z; acc[3][3] += a.w * b.w;
        }
        __syncthreads();
    }
    float* Cf = Gp + (size_t)bz * 65536;
    #pragma unroll
    for (int i = 0; i < 4; ++i) {
        const int m = m0 + tm * 4 + i;
        *(float4*)&Cf[(size_t)m * 256 + n0 + tn * 4] =
            make_float4(acc[i][0], acc[i][1], acc[i][2], acc[i][3]);
    }
}

__global__ __launch_bounds__(256)
void greduce_k(const float* __restrict__ Gp, float* __restrict__ G)
{
    const size_t i = (size_t)blockIdx.x * 256 + threadIdx.x;
    float s = 0.f;
    #pragma unroll
    for (int sp = 0; sp < 8; ++sp) s += Gp[(size_t)sp * 524288 + i];
    G[i] = s;
}

__global__ __launch_bounds__(256)
void cam_softmax_k(const float* __restrict__ G, float* __restrict__ attsum)
{
    __shared__ float rmn[4], rsm[4];
    const int c = blockIdx.x, b = blockIdx.y;
    const int d = threadIdx.x;
    float acc = 0.f;
    for (int s = 0; s < 4; ++s) {
        const float* row = G + (((size_t)(s * 2 + b)) * 256 + c) * 256;
        const float e = row[d];
        float mn = e;
        for (int o = 32; o; o >>= 1) mn = fminf(mn, __shfl_down(mn, o));
        if ((d & 63) == 0) rmn[d >> 6] = mn;
        __syncthreads();
        mn = fminf(fminf(rmn[0], rmn[1]), fminf(rmn[2], rmn[3]));
        const float ex = __expf(mn - e);
        float sm = ex;
        for (int o = 32; o; o >>= 1) sm += __shfl_down(sm, o);
        if ((d & 63) == 0) rsm[d >> 6] = sm;
        __syncthreads();
        sm = rsm[0] + rsm[1] + rsm[2] + rsm[3];
        acc += ex * (1.0f / sm);
        __syncthreads();
    }
    attsum[((size_t)b * 256 + c) * 256 + d] = acc;
}

// ================= transpose-add: Y[c][n] += Yt[n][c] =================
__global__ __launch_bounds__(256)
void transT_k(const float* __restrict__ Yt, float* __restrict__ Y)
{
    __shared__ float tile[64][65];
    const int sb = blockIdx.z;
    const int n0 = blockIdx.x * 64, c0 = blockIdx.y * 64;
    const float* src = Yt + (size_t)sb * ((size_t)HW * 256);
    float* dst = Y + (size_t)sb * ((size_t)256 * HW);
    const int t = threadIdx.x;
    {
        const int n = t >> 2, p = t & 3;
        const float4* s4 = (const float4*)&src[(size_t)(n0 + n) * 256 + c0 + p * 16];
        #pragma unroll
        for (int i = 0; i < 4; ++i) {
            const float4 v = s4[i];
            tile[n][p * 16 + i * 4 + 0] = v.x;
            tile[n][p * 16 + i * 4 + 1] = v.y;
            tile[n][p * 16 + i * 4 + 2] = v.z;
            tile[n][p * 16 + i * 4 + 3] = v.w;
        }
    }
    __syncthreads();
    const int c = t >> 2, p = t & 3;
    #pragma unroll
    for (int i = 0; i < 4; ++i) {
        float* dp = &dst[(size_t)(c0 + c) * HW + n0 + p * 16 + i * 4];
        float4 cur = *(float4*)dp;
        cur.x += tile[p * 16 + i * 4 + 0][c];
        cur.y += tile[p * 16 + i * 4 + 1][c];
        cur.z += tile[p * 16 + i * 4 + 2][c];
        cur.w += tile[p * 16 + i * 4 + 3][c];
        *(float4*)dp = cur;
    }
}

// ================= im2col: colT[n][k] row-major bf16 =================
__global__ __launch_bounds__(256)
void im2col_k(const float* __restrict__ Y, u16* __restrict__ colT, int sb0)
{
    const int id = blockIdx.x * 256 + threadIdx.x;   // n*288 + kg
    const int sbl = blockIdx.z;
    const int kg = id % 288, n = id / 288;
    const float* Yb = Y + (size_t)(sb0 + sbl) * ((size_t)256 * HW);
    const int h = n >> 6, wc = n & 63;
    u16 out[8];
    #pragma unroll
    for (int kl = 0; kl < 8; ++kl) {
        const int k = kg * 8 + kl;
        const int ic = k / 9, r = k - ic * 9;
        const int ih = h + r / 3 - 1, iw = wc + (r % 3) - 1;
        float v = 0.f;
        if (ih >= 0 && ih < 64 && iw >= 0 && iw < 64)
            v = Yb[(size_t)ic * HW + (ih << 6) + iw];
        out[kl] = f2bf(v);
    }
    *(u16x8*)&colT[((size_t)sbl * HW + n) * 2304 + kg * 8] = *(u16x8*)out;
}

// ================= flat f32 -> bf16 =================
__global__ __launch_bounds__(256)
void cvt_k(const float* __restrict__ s, u16* __restrict__ d)
{
    const size_t i = ((size_t)blockIdx.x * 256 + threadIdx.x) * 4;
    const float4 v = *(const float4*)&s[i];
    u16 o[4] = { f2bf(v.x), f2bf(v.y), f2bf(v.z), f2bf(v.w) };
    *(u16x4*)&d[i] = *(u16x4*)o;
}

extern "C" void kernel_launch(void* const* d_in, const int* in_sizes, int n_in,
                              void* d_out, int out_size, void* d_ws, size_t ws_size,
                              hipStream_t stream)
{
    XPtrs xs;
    xs.p[0] = (const float*)d_in[0];
    xs.p[1] = (const float*)d_in[1];
    xs.p[2] = (const float*)d_in[2];
    xs.p[3] = (const float*)d_in[3];
    const float* Wq = (const float*)d_in[4];
    const float* bq = (const float*)d_in[5];
    const float* Wk = (const float*)d_in[6];
    const float* bk = (const float*)d_in[7];
    const float* Wv = (const float*)d_in[8];
    const float* bv = (const float*)d_in[9];
    const float* gp = (const float*)d_in[10];
    const float* gc = (const float*)d_in[11];
    const float* Wd = (const float*)d_in[12];
    const float* bd = (const float*)d_in[13];

    char* base = (char*)d_ws;
    size_t off = 0;
    auto alloc = [&](size_t bytes) -> char* {
        char* p = base + off;
        off = (off + bytes + 255) & ~(size_t)255;
        return p;
    };

    // persistent through conv
    float* Y    = (float*)alloc((size_t)8 * 256 * HW * 4);      // 32 MB
    u16*   Wdh  = (u16*)  alloc((size_t)256 * 2304 * 2);        // 1.1 MB
    u16*   attH = (u16*)  alloc((size_t)2 * 65536 * 2);         // 0.25 MB
    const size_t overlayStart = off;
    // dead before conv
    u16*   Xt   = (u16*)  alloc((size_t)8 * HW * 256 * 2);      // 16 MB
    u16*   QKt  = (u16*)  alloc((size_t)8 * HW * 64 * 2);       // 4 MB
    u16*   Vh   = (u16*)  alloc((size_t)8 * 256 * HW * 2);      // 16 MB
    float* Yt   = (float*)alloc((size_t)8 * HW * 256 * 4);      // 32 MB
    float* Gp   = (float*)alloc((size_t)64 * 65536 * 4);        // 16 MB
    float* G    = (float*)alloc((size_t)8 * 65536 * 4);         // 2 MB
    float* att  = (float*)alloc((size_t)2 * 65536 * 4);         // 0.5 MB
    u16*   Wqkh = (u16*)  alloc((size_t)64 * 256 * 2);
    u16*   Wvh  = (u16*)  alloc((size_t)256 * 256 * 2);
    // ~120 MB total

    const size_t colPer = (size_t)HW * 2304 * 2;                // 18.9 MB / sb
    u16* colT = (u16*)(base + overlayStart);
    long nchunkL = (long)((ws_size - overlayStart) / colPer);
    const int nchunk = (int)(nchunkL > 8 ? 8 : (nchunkL < 1 ? 1 : nchunkL));

    dim3 T(256);

    // prep + weight converts
    prep_k<<<dim3(64, 4, 8), T, 0, stream>>>(xs, Xt);
    cvt_k<<<dim3(8),   T, 0, stream>>>(Wq, Wqkh);
    cvt_k<<<dim3(8),   T, 0, stream>>>(Wk, Wqkh + 8192);
    cvt_k<<<dim3(64),  T, 0, stream>>>(Wv, Wvh);
    cvt_k<<<dim3(576), T, 0, stream>>>(Wd, Wdh);

    // CAM attention matrix (f32 path)
    gram_k<<<dim3(4, 4, 64), T, 0, stream>>>(Gp, xs);
    greduce_k<<<dim3(2048), T, 0, stream>>>(Gp, G);
    cam_softmax_k<<<dim3(256, 2), T, 0, stream>>>(G, att);
    cvt_k<<<dim3(128), T, 0, stream>>>(att, attH);

    // projections (MFMA)
    mm_k<MM_QK><<<dim3(1, 32, 8), T, 0, stream>>>(Xt, Wqkh, QKt, bq, bk, nullptr, xs,
                                                  256, 256, 256,
                                                  (long)HW * 256, 0, (long)HW * 64, 0);
    mm_k<MM_V><<<dim3(32, 2, 8), T, 0, stream>>>(Wvh, Xt, Vh, bv, nullptr, nullptr, xs,
                                                 256, 256, 256,
                                                 0, (long)HW * 256, (long)256 * HW, 0);

    // fused flash PAM
    flash_k<<<dim3(64, 8), dim3(512), 0, stream>>>(QKt, Vh, Yt, gp);

    // CAM apply: Y = gc * attsum[b] @ X + 5X   (MFMA)
    mm_k<MM_CAM><<<dim3(32, 2, 8), T, 0, stream>>>(attH, Xt, Y, nullptr, nullptr, gc, xs,
                                                   256, 256, 256,
                                                   65536, (long)HW * 256, (long)256 * HW, 0);

    // Y += Yt^T  (PAM contribution)
    transT_k<<<dim3(64, 4, 8), T, 0, stream>>>(Yt, Y);

    // 3x3 conv: im2col (row-major bf16 patches) + MFMA GEMM, chunked
    for (int c0 = 0; c0 < 8; c0 += nchunk) {
        const int cs = (8 - c0 < nchunk) ? (8 - c0) : nchunk;
        im2col_k<<<dim3(4608, 1, cs), T, 0, stream>>>(Y, colT, c0);
        mm_k<MM_CONV><<<dim3(32, 2, cs), T, 0, stream>>>(Wdh, colT, d_out, bd, nullptr, nullptr, xs,
                                                         2304, 2304, 2304,
                                                         0, (long)HW * 2304, (long)256 * HW, c0);
    }
}

// Round 7
// 470.067 us; speedup vs baseline: 1.8441x; 1.8441x over previous
//
#include <hip/hip_runtime.h>

// FeatureEnhance: 4-stream PAM + CAM + shared 3x3 conv.
// S=4, B=2, C=256, CQ=32, H=W=64, N=HW=4096.
// Round 7: fix tqkT_k half-tile load bug (rows 32-63 of LDS tile were
// uninitialized -> NaN). Otherwise identical to round 6: uniform-wave flash,
// packed-K8 MFMA GEMMs, f32 split-K GRAM.

#define HW 4096

typedef unsigned short u16;
typedef __attribute__((ext_vector_type(4))) float f32x4;
typedef __attribute__((ext_vector_type(8))) short bf16x8;
typedef __attribute__((ext_vector_type(8))) unsigned short u16x8;
typedef __attribute__((ext_vector_type(4))) unsigned short u16x4;

__device__ __forceinline__ float bf2f(u16 u) { return __uint_as_float(((unsigned)u) << 16); }
__device__ __forceinline__ u16 f2bf(float f) {
    unsigned x = __float_as_uint(f);
    return (u16)((x + 0x7fffu + ((x >> 16) & 1u)) >> 16);
}
__device__ __forceinline__ void gload16(const void* g, void* l) {
    __builtin_amdgcn_global_load_lds((const __attribute__((address_space(1))) void*)g,
                                     (__attribute__((address_space(3))) void*)l, 16, 0, 0);
}

struct XPtrs { const float* p[4]; };

// ============ packed-K8 MFMA GEMM: C[m,n] = sum_k A[m,k]*Bpack[k,n] ============
// A bf16 row-major (lda). Bpack: [k>>3][n(4096)][k&7]. BM=BN=128, BK=32, 4 waves.
enum { PM_QK = 0, PM_V = 1, PM_CAM = 2, PM_CONV = 3 };

template<int MODE>
__global__ __launch_bounds__(256)
void mfma_p_k(const u16* __restrict__ A, const u16* __restrict__ Bp,
              void* __restrict__ Cp,
              const float* __restrict__ b0, const float* __restrict__ b1,
              const float* __restrict__ gscale, XPtrs xs,
              int K, int lda, long aBatch, long bBatch, long cBatch, int sb0)
{
    const int n0 = blockIdx.x * 128, m0 = blockIdx.y * 128, z = blockIdx.z;
    const u16* Ab = A + (MODE == PM_CAM ? (size_t)(z & 1) * aBatch : (size_t)z * aBatch)
                      + (size_t)m0 * lda;
    const u16* Bb = Bp + (size_t)z * bBatch + (size_t)n0 * 8;

    __shared__ u16 As[4096];   // [kh][m][kl]
    __shared__ u16 Bs[4096];   // [kh][n][kl]

    const int t = threadIdx.x, lane = t & 63, w = t >> 6;
    const int mw = (w >> 1) * 64, nw = (w & 1) * 64;
    const int l15 = lane & 15, l4 = lane >> 4;

    f32x4 acc[4][4] = {};

    const u16* gaw = Ab + (size_t)lane * lda + w * 8;
    const u16* gbw = Bb + (size_t)w * (HW * 8) + (size_t)lane * 8;

    for (int kb = 0; kb < K; kb += 32) {
        gload16(gaw + kb,                    &As[w * 1024]);
        gload16(gaw + kb + (size_t)64 * lda, &As[w * 1024 + 512]);
        const u16* gb = gbw + (size_t)(kb >> 3) * (HW * 8);
        gload16(gb,       &Bs[w * 1024]);
        gload16(gb + 512, &Bs[w * 1024 + 512]);
        __syncthreads();

        bf16x8 af[4], bf[4];
        #pragma unroll
        for (int i = 0; i < 4; ++i) {
            af[i] = *(const bf16x8*)&As[l4 * 1024 + (mw + i * 16 + l15) * 8];
            bf[i] = *(const bf16x8*)&Bs[l4 * 1024 + (nw + i * 16 + l15) * 8];
        }
        #pragma unroll
        for (int mi = 0; mi < 4; ++mi)
            #pragma unroll
            for (int ni = 0; ni < 4; ++ni)
                acc[mi][ni] = __builtin_amdgcn_mfma_f32_16x16x32_bf16(af[mi], bf[ni], acc[mi][ni], 0, 0, 0);
        __syncthreads();
    }

    #pragma unroll
    for (int mi = 0; mi < 4; ++mi) {
        #pragma unroll
        for (int ni = 0; ni < 4; ++ni) {
            #pragma unroll
            for (int r = 0; r < 4; ++r) {
                const int row = m0 + mw + mi * 16 + l4 * 4 + r;
                const int col = n0 + nw + ni * 16 + l15;
                float v = acc[mi][ni][r];
                if constexpr (MODE == PM_QK) {
                    if (row < 64) {
                        v += (row < 32) ? b0[row] : b1[row - 32];
                        ((u16*)Cp)[(size_t)z * cBatch + (size_t)row * HW + col] = f2bf(v);
                    }
                } else if constexpr (MODE == PM_V) {
                    v += b0[row];
                    ((u16*)Cp)[(size_t)z * cBatch + (size_t)row * HW + col] = f2bf(v);
                } else if constexpr (MODE == PM_CAM) {
                    const float* xb = xs.p[z >> 1] + (size_t)(z & 1) * (256 * HW);
                    v = gscale[0] * v + 5.f * xb[(size_t)row * HW + col];
                    ((float*)Cp)[(size_t)z * cBatch + (size_t)row * HW + col] = v;
                } else { // PM_CONV
                    v += b0[row];
                    ((float*)Cp)[(size_t)(sb0 + z) * cBatch + (size_t)row * HW + col] = v;
                }
            }
        }
    }
}

// ============ uniform-wave flash: Yt[n][c] = gp * softmax(Q K^T) @ V^T ============
// QKt: [sb][4096][64] bf16 (cols 0-31 Q, 32-63 K). Vh: [sb][256][4096] bf16.
// 8 waves, each owns 16 q-rows: QK + in-register softmax + private P + full PV.
// Barriers only around the shared V tile.
__global__ __launch_bounds__(512, 2)
void flash_k(const u16* __restrict__ QKt, const u16* __restrict__ Vh,
             float* __restrict__ Yt, const float* __restrict__ gscale)
{
    __shared__ u16 Vs[256 * 128];     // 64KB: [c][slot ^ (c&7)][8]
    __shared__ u16 Ps[8][16 * 128];   // 32KB per-wave: [qrow][slot ^ (qrow&7)][8]

    const int sb = blockIdx.y;
    const int t = threadIdx.x, w = t >> 6, lane = t & 63;
    const int l15 = lane & 15, l4 = lane >> 4;
    const int q0 = blockIdx.x * 128 + w * 16;

    const u16* QKb = QKt + (size_t)sb * ((size_t)HW * 64);
    const u16* Vb  = Vh + (size_t)sb * ((size_t)256 * HW);
    float* Yb = Yt + (size_t)sb * ((size_t)HW * 256);

    const bf16x8 aq = *(const bf16x8*)&QKb[(size_t)(q0 + l15) * 64 + l4 * 8];

    f32x4 acc[16] = {};
    float mrun[4], lrun[4];
    #pragma unroll
    for (int r = 0; r < 4; ++r) { mrun[r] = -3.0e38f; lrun[r] = 0.f; }

    const f32x4 zero4 = {0.f, 0.f, 0.f, 0.f};
    u16* Pw = Ps[w];

    for (int it = 0; it < 32; ++it) {
        const int m0 = it * 128;

        // stage shared V tile [256][128] -> LDS (pre-swizzled source, linear dest)
        #pragma unroll
        for (int i = 0; i < 8; ++i) {
            const int chunk = i * 512 + t;
            const int c = chunk >> 4, kc = chunk & 15;
            const int mo = kc ^ (c & 7);
            gload16(Vb + (size_t)c * HW + m0 + mo * 8, &Vs[(i * 512 + w * 64) * 8]);
        }

        // QK for this wave's 16 q-rows x 128 kv
        f32x4 s[8];
        #pragma unroll
        for (int j = 0; j < 8; ++j) {
            const bf16x8 bk = *(const bf16x8*)&QKb[(size_t)(m0 + j * 16 + l15) * 64 + 32 + l4 * 8];
            s[j] = __builtin_amdgcn_mfma_f32_16x16x32_bf16(aq, bk, zero4, 0, 0, 0);
        }

        // online softmax, P -> wave-private swizzled LDS (no barrier needed)
        #pragma unroll
        for (int r = 0; r < 4; ++r) {
            float tmax = fmaxf(fmaxf(s[0][r], s[1][r]), fmaxf(s[2][r], s[3][r]));
            tmax = fmaxf(tmax, fmaxf(fmaxf(s[4][r], s[5][r]), fmaxf(s[6][r], s[7][r])));
            tmax = fmaxf(tmax, __shfl_xor(tmax, 1));
            tmax = fmaxf(tmax, __shfl_xor(tmax, 2));
            tmax = fmaxf(tmax, __shfl_xor(tmax, 4));
            tmax = fmaxf(tmax, __shfl_xor(tmax, 8));
            const float mnew = fmaxf(mrun[r], tmax);
            const float scl = __expf(mrun[r] - mnew);
            mrun[r] = mnew;
            const int qrow = l4 * 4 + r;
            float tsum = 0.f;
            #pragma unroll
            for (int j = 0; j < 8; ++j) {
                const float p = __expf(s[j][r] - mnew);
                tsum += p;
                const int sl = (j * 2 + (l15 >> 3)) ^ (qrow & 7);
                Pw[qrow * 128 + sl * 8 + (l15 & 7)] = f2bf(p);
            }
            tsum += __shfl_xor(tsum, 1);
            tsum += __shfl_xor(tsum, 2);
            tsum += __shfl_xor(tsum, 4);
            tsum += __shfl_xor(tsum, 8);
            lrun[r] = lrun[r] * scl + tsum;
            #pragma unroll
            for (int ct = 0; ct < 16; ++ct) acc[ct][r] *= scl;
        }
        __syncthreads();   // V tile staged & visible

        // PV: this wave's 16 q-rows x all 256 channels
        #pragma unroll
        for (int ks = 0; ks < 4; ++ks) {
            const bf16x8 ap = *(const bf16x8*)&Pw[l15 * 128 + (((ks * 4 + l4) ^ (l15 & 7)) << 3)];
            #pragma unroll
            for (int ct = 0; ct < 16; ++ct) {
                const int c = ct * 16 + l15;
                const bf16x8 bv = *(const bf16x8*)&Vs[c * 128 + (((ks * 4 + l4) ^ (c & 7)) << 3)];
                acc[ct] = __builtin_amdgcn_mfma_f32_16x16x32_bf16(ap, bv, acc[ct], 0, 0, 0);
            }
        }
        __syncthreads();   // done reading Vs before next stage
    }

    const float gp = gscale[0];
    #pragma unroll
    for (int r = 0; r < 4; ++r) {
        const float sc = gp / lrun[r];
        const int row = q0 + l4 * 4 + r;
        #pragma unroll
        for (int ct = 0; ct < 16; ++ct)
            Yb[(size_t)row * 256 + ct * 16 + l15] = acc[ct][r] * sc;
    }
}

// ============ X pack: X f32 [c][4096] -> Xp bf16 [c>>3][n][c&7] ============
__global__ __launch_bounds__(256)
void xpack_k(XPtrs xs, u16* __restrict__ Xp)
{
    __shared__ float tile[64][65];
    const int sb = blockIdx.z;
    const int n0 = blockIdx.x * 64, c0 = blockIdx.y * 64;
    const float* X = xs.p[sb >> 1] + (size_t)(sb & 1) * (256 * HW);
    u16* Xo = Xp + (size_t)sb * ((size_t)32 * HW * 8);
    const int t = threadIdx.x;
    {
        const int c = t >> 2, p = t & 3;
        const float4* s4 = (const float4*)&X[(size_t)(c0 + c) * HW + n0 + p * 16];
        #pragma unroll
        for (int i = 0; i < 4; ++i) {
            const float4 v = s4[i];
            tile[c][p * 16 + i * 4 + 0] = v.x;
            tile[c][p * 16 + i * 4 + 1] = v.y;
            tile[c][p * 16 + i * 4 + 2] = v.z;
            tile[c][p * 16 + i * 4 + 3] = v.w;
        }
    }
    __syncthreads();
    const int n = t >> 2;
    #pragma unroll
    for (int pp = 0; pp < 2; ++pp) {
        const int cg = (t & 3) * 2 + pp;
        u16 o[8];
        #pragma unroll
        for (int cl = 0; cl < 8; ++cl) o[cl] = f2bf(tile[cg * 8 + cl][n]);
        *(u16x8*)&Xo[(((size_t)(c0 >> 3) + cg) * HW + (n0 + n)) * 8] = *(u16x8*)o;
    }
}

// ============ bf16 transpose: QKc [64][4096] -> QKt [4096][64] per sb ============
__global__ __launch_bounds__(256)
void tqkT_k(const u16* __restrict__ src, u16* __restrict__ dst)
{
    __shared__ u16 tile[64][72];
    const int sb = blockIdx.y;
    const int n0 = blockIdx.x * 64;
    const u16* s = src + (size_t)sb * (64 * HW);
    u16* d = dst + (size_t)sb * (HW * 64);
    const int t = threadIdx.x;
    // load ALL 64 rows (round-6 bug: only rows 0-31 were loaded)
    #pragma unroll
    for (int p = 0; p < 2; ++p) {
        const int c = (t >> 3) + p * 32, nn = (t & 7) * 8;
        const u16x8 v = *(const u16x8*)&s[(size_t)c * HW + n0 + nn];
        *(u16x8*)&tile[c][nn] = v;
    }
    __syncthreads();
    const int n = t >> 2, co = (t & 3) * 16;
    u16 o[16];
    #pragma unroll
    for (int j = 0; j < 16; ++j) o[j] = tile[co + j][n];
    *(u16x8*)&d[(size_t)(n0 + n) * 64 + co]     = *(u16x8*)&o[0];
    *(u16x8*)&d[(size_t)(n0 + n) * 64 + co + 8] = *(u16x8*)&o[8];
}

// ============ f32 split-K GRAM (precision-critical) ============
__global__ __launch_bounds__(256)
void gram_k(float* __restrict__ Gp, XPtrs xs)
{
    const int bx = blockIdx.x, by = blockIdx.y, bz = blockIdx.z;
    const int sbi = bz & 7;
    const int n0 = bx * 64, m0 = by * 64;
    const int t = threadIdx.x;
    const int tm = t >> 4, tn = t & 15;
    const float* xb = xs.p[sbi >> 1] + (size_t)(sbi & 1) * (256 * HW) + (bz >> 3) * 512;

    __shared__ float As[16][68];
    __shared__ float Bs[16][68];
    float acc[4][4] = {};

    for (int kb = 0; kb < 512; kb += 16) {
        {
            const int m = t >> 2, k0 = (t & 3) * 4;
            float4 v = *(const float4*)(xb + (size_t)(m0 + m) * HW + (kb + k0));
            As[k0 + 0][m] = v.x; As[k0 + 1][m] = v.y; As[k0 + 2][m] = v.z; As[k0 + 3][m] = v.w;
        }
        {
            const int n = t >> 2, k0 = (t & 3) * 4;
            float4 v = *(const float4*)(xb + (size_t)(n0 + n) * HW + (kb + k0));
            Bs[k0 + 0][n] = v.x; Bs[k0 + 1][n] = v.y; Bs[k0 + 2][n] = v.z; Bs[k0 + 3][n] = v.w;
        }
        __syncthreads();
        #pragma unroll
        for (int k = 0; k < 16; ++k) {
            const float4 a = *(const float4*)&As[k][tm * 4];
            const float4 b = *(const float4*)&Bs[k][tn * 4];
            acc[0][0] += a.x * b.x; acc[0][1] += a.x * b.y; acc[0][2] += a.x * b.z; acc[0][3] += a.x * b.w;
            acc[1][0] += a.y * b.x; acc[1][1] += a.y * b.y; acc[1][2] += a.y * b.z; acc[1][3] += a.y * b.w;
            acc[2][0] += a.z * b.x; acc[2][1] += a.z * b.y; acc[2][2] += a.z * b.z; acc[2][3] += a.z * b.w;
            acc[3][0] += a.w * b.x; acc[3][1] += a.w * b.y; acc[3][2] += a.w * b.z; acc[3][3] += a.w * b.w;
        }
        __syncthreads();
    }
    float* Cf = Gp + (size_t)bz * 65536;
    #pragma unroll
    for (int i = 0; i < 4; ++i) {
        const int m = m0 + tm * 4 + i;
        *(float4*)&Cf[(size_t)m * 256 + n0 + tn * 4] =
            make_float4(acc[i][0], acc[i][1], acc[i][2], acc[i][3]);
    }
}

__global__ __launch_bounds__(256)
void greduce_k(const float* __restrict__ Gp, float* __restrict__ G)
{
    const size_t i = (size_t)blockIdx.x * 256 + threadIdx.x;
    float s = 0.f;
    #pragma unroll
    for (int sp = 0; sp < 8; ++sp) s += Gp[(size_t)sp * 524288 + i];
    G[i] = s;
}

__global__ __launch_bounds__(256)
void cam_softmax_k(const float* __restrict__ G, float* __restrict__ attsum)
{
    __shared__ float rmn[4], rsm[4];
    const int c = blockIdx.x, b = blockIdx.y;
    const int d = threadIdx.x;
    float acc = 0.f;
    for (int s = 0; s < 4; ++s) {
        const float* row = G + (((size_t)(s * 2 + b)) * 256 + c) * 256;
        const float e = row[d];
        float mn = e;
        for (int o = 32; o; o >>= 1) mn = fminf(mn, __shfl_down(mn, o));
        if ((d & 63) == 0) rmn[d >> 6] = mn;
        __syncthreads();
        mn = fminf(fminf(rmn[0], rmn[1]), fminf(rmn[2], rmn[3]));
        const float ex = __expf(mn - e);
        float sm = ex;
        for (int o = 32; o; o >>= 1) sm += __shfl_down(sm, o);
        if ((d & 63) == 0) rsm[d >> 6] = sm;
        __syncthreads();
        sm = rsm[0] + rsm[1] + rsm[2] + rsm[3];
        acc += ex * (1.0f / sm);
        __syncthreads();
    }
    attsum[((size_t)b * 256 + c) * 256 + d] = acc;
}

// ============ transpose-add: Y[c][n] += Yt[n][c] ============
__global__ __launch_bounds__(256)
void transT_k(const float* __restrict__ Yt, float* __restrict__ Y)
{
    __shared__ float tile[64][65];
    const int sb = blockIdx.z;
    const int n0 = blockIdx.x * 64, c0 = blockIdx.y * 64;
    const float* src = Yt + (size_t)sb * ((size_t)HW * 256);
    float* dst = Y + (size_t)sb * ((size_t)256 * HW);
    const int t = threadIdx.x;
    {
        const int n = t >> 2, p = t & 3;
        const float4* s4 = (const float4*)&src[(size_t)(n0 + n) * 256 + c0 + p * 16];
        #pragma unroll
        for (int i = 0; i < 4; ++i) {
            const float4 v = s4[i];
            tile[n][p * 16 + i * 4 + 0] = v.x;
            tile[n][p * 16 + i * 4 + 1] = v.y;
            tile[n][p * 16 + i * 4 + 2] = v.z;
            tile[n][p * 16 + i * 4 + 3] = v.w;
        }
    }
    __syncthreads();
    const int c = t >> 2, p = t & 3;
    #pragma unroll
    for (int i = 0; i < 4; ++i) {
        float* dp = &dst[(size_t)(c0 + c) * HW + n0 + p * 16 + i * 4];
        float4 cur = *(float4*)dp;
        cur.x += tile[p * 16 + i * 4 + 0][c];
        cur.y += tile[p * 16 + i * 4 + 1][c];
        cur.z += tile[p * 16 + i * 4 + 2][c];
        cur.w += tile[p * 16 + i * 4 + 3][c];
        *(float4*)dp = cur;
    }
}

// ============ im2col (bf16, packed-K8): col[kg][n][kl] ============
__global__ __launch_bounds__(256)
void im2col_k(const float* __restrict__ Y, u16* __restrict__ col, int sb0)
{
    const int n = blockIdx.x * 256 + threadIdx.x;
    const int kg = blockIdx.y;
    const int sbl = blockIdx.z;
    const float* Yb = Y + (size_t)(sb0 + sbl) * ((size_t)256 * HW);
    const int h = n >> 6, wc = n & 63;
    u16 out[8];
    #pragma unroll
    for (int kl = 0; kl < 8; ++kl) {
        const int k = kg * 8 + kl;
        const int ic = k / 9, r = k - ic * 9;
        const int ih = h + r / 3 - 1, iw = wc + (r % 3) - 1;
        float v = 0.f;
        if (ih >= 0 && ih < 64 && iw >= 0 && iw < 64)
            v = Yb[(size_t)ic * HW + (ih << 6) + iw];
        out[kl] = f2bf(v);
    }
    *(u16x8*)&col[(((size_t)sbl * 288 + kg) * HW + n) * 8] = *(u16x8*)out;
}

// ============ flat f32 -> bf16 ============
__global__ __launch_bounds__(256)
void cvt_k(const float* __restrict__ s, u16* __restrict__ d)
{
    const size_t i = ((size_t)blockIdx.x * 256 + threadIdx.x) * 4;
    const float4 v = *(const float4*)&s[i];
    u16 o[4] = { f2bf(v.x), f2bf(v.y), f2bf(v.z), f2bf(v.w) };
    *(u16x4*)&d[i] = *(u16x4*)o;
}

extern "C" void kernel_launch(void* const* d_in, const int* in_sizes, int n_in,
                              void* d_out, int out_size, void* d_ws, size_t ws_size,
                              hipStream_t stream)
{
    XPtrs xs;
    xs.p[0] = (const float*)d_in[0];
    xs.p[1] = (const float*)d_in[1];
    xs.p[2] = (const float*)d_in[2];
    xs.p[3] = (const float*)d_in[3];
    const float* Wq = (const float*)d_in[4];
    const float* bq = (const float*)d_in[5];
    const float* Wk = (const float*)d_in[6];
    const float* bk = (const float*)d_in[7];
    const float* Wv = (const float*)d_in[8];
    const float* bv = (const float*)d_in[9];
    const float* gp = (const float*)d_in[10];
    const float* gc = (const float*)d_in[11];
    const float* Wd = (const float*)d_in[12];
    const float* bd = (const float*)d_in[13];

    char* base = (char*)d_ws;
    size_t off = 0;
    auto alloc = [&](size_t bytes) -> char* {
        char* p = base + off;
        off = (off + bytes + 255) & ~(size_t)255;
        return p;
    };

    // persistent through conv
    float* Y    = (float*)alloc((size_t)8 * 256 * HW * 4);      // 32 MB
    u16*   Wdh  = (u16*)  alloc((size_t)256 * 2304 * 2);        // 1.2 MB
    const size_t overlayStart = off;
    // dead before conv
    u16*   Xp   = (u16*)  alloc((size_t)8 * 32 * HW * 8 * 2);   // 16 MB
    u16*   Vh   = (u16*)  alloc((size_t)8 * 256 * HW * 2);      // 16 MB
    float* Yt   = (float*)alloc((size_t)8 * HW * 256 * 4);      // 32 MB
    u16*   QKc  = (u16*)  alloc((size_t)8 * 64 * HW * 2);       // 4 MB
    u16*   QKt  = (u16*)  alloc((size_t)8 * HW * 64 * 2);       // 4 MB
    float* Gp   = (float*)alloc((size_t)64 * 65536 * 4);        // 16 MB
    float* G    = (float*)alloc((size_t)8 * 65536 * 4);         // 2 MB
    float* att  = (float*)alloc((size_t)2 * 65536 * 4);         // 0.5 MB
    u16*   attH = (u16*)  alloc((size_t)2 * 65536 * 2);         // 0.25 MB
    u16*   Wqkh = (u16*)  alloc((size_t)128 * 256 * 2);         // 64 KB (rows 64-127 pad)
    u16*   Wvh  = (u16*)  alloc((size_t)256 * 256 * 2);         // 128 KB
    // ~124.5 MB total

    const size_t colPer = (size_t)288 * HW * 8 * 2;             // 18.9 MB / sb
    u16* colp = (u16*)(base + overlayStart);
    long nchunkL = (long)((ws_size - overlayStart) / colPer);
    const int nchunk = (int)(nchunkL > 8 ? 8 : (nchunkL < 1 ? 1 : nchunkL));

    dim3 T(256);

    // packs + weight converts
    xpack_k<<<dim3(64, 4, 8), T, 0, stream>>>(xs, Xp);
    cvt_k<<<dim3(8),   T, 0, stream>>>(Wq, Wqkh);
    cvt_k<<<dim3(8),   T, 0, stream>>>(Wk, Wqkh + 32 * 256);
    cvt_k<<<dim3(64),  T, 0, stream>>>(Wv, Wvh);
    cvt_k<<<dim3(576), T, 0, stream>>>(Wd, Wdh);

    // CAM attention matrix (f32 path)
    gram_k<<<dim3(4, 4, 64), T, 0, stream>>>(Gp, xs);
    greduce_k<<<dim3(2048), T, 0, stream>>>(Gp, G);
    cam_softmax_k<<<dim3(256, 2), T, 0, stream>>>(G, att);
    cvt_k<<<dim3(128), T, 0, stream>>>(att, attH);

    // projections (packed-B MFMA)
    mfma_p_k<PM_QK><<<dim3(32, 1, 8), T, 0, stream>>>(Wqkh, Xp, QKc, bq, bk, nullptr, xs,
                                                      256, 256, 0, (long)32 * HW * 8, (long)64 * HW, 0);
    tqkT_k<<<dim3(64, 8), T, 0, stream>>>(QKc, QKt);
    mfma_p_k<PM_V><<<dim3(32, 2, 8), T, 0, stream>>>(Wvh, Xp, Vh, bv, nullptr, nullptr, xs,
                                                     256, 256, 0, (long)32 * HW * 8, (long)256 * HW, 0);

    // fused flash PAM (uniform waves)
    flash_k<<<dim3(32, 8), dim3(512), 0, stream>>>(QKt, Vh, Yt, gp);

    // CAM apply: Y = gc * attsum[b] @ X + 5X   (packed-B MFMA)
    mfma_p_k<PM_CAM><<<dim3(32, 2, 8), T, 0, stream>>>(attH, Xp, Y, nullptr, nullptr, gc, xs,
                                                       256, 256, 65536, (long)32 * HW * 8, (long)256 * HW, 0);

    // Y += Yt^T  (PAM contribution)
    transT_k<<<dim3(64, 4, 8), T, 0, stream>>>(Yt, Y);

    // 3x3 conv: packed im2col + MFMA GEMM, chunked by ws capacity
    for (int c0 = 0; c0 < 8; c0 += nchunk) {
        const int cs = (8 - c0 < nchunk) ? (8 - c0) : nchunk;
        im2col_k<<<dim3(16, 288, cs), T, 0, stream>>>(Y, colp, c0);
        mfma_p_k<PM_CONV><<<dim3(32, 2, cs), T, 0, stream>>>(Wdh, colp, d_out, bd, nullptr, nullptr, xs,
                                                             2304, 2304, 0, (long)288 * HW * 8, (long)256 * HW, c0);
    }
}

// Round 9
// 460.643 us; speedup vs baseline: 1.8818x; 1.0205x over previous
//
#include <hip/hip_runtime.h>

// FeatureEnhance: 4-stream PAM + CAM + shared 3x3 conv.
// S=4, B=2, C=256, CQ=32, H=W=64, N=HW=4096.
// Round 9: flash v5 = round-8 math (swapped QK, direct-exp softmax, cvt_pk +
// ds_bpermute in-register P, packed linear V) on round-7 sync (single V
// buffer, 2 barriers/iter — race-free by construction; r8's dbuf single-
// barrier failed post-timing revalidation). 64KB LDS -> 2 blocks/CU.
// Rest identical to round 7 (passed 470us) + r8's validated PM_V pack.

#define HW 4096

typedef unsigned short u16;
typedef __attribute__((ext_vector_type(4))) float f32x4;
typedef __attribute__((ext_vector_type(8))) short bf16x8;
typedef __attribute__((ext_vector_type(4))) unsigned u32x4;
typedef __attribute__((ext_vector_type(8))) unsigned short u16x8;
typedef __attribute__((ext_vector_type(4))) unsigned short u16x4;

__device__ __forceinline__ float bf2f(u16 u) { return __uint_as_float(((unsigned)u) << 16); }
__device__ __forceinline__ u16 f2bf(float f) {
    unsigned x = __float_as_uint(f);
    return (u16)((x + 0x7fffu + ((x >> 16) & 1u)) >> 16);
}
__device__ __forceinline__ void gload16(const void* g, void* l) {
    __builtin_amdgcn_global_load_lds((const __attribute__((address_space(1))) void*)g,
                                     (__attribute__((address_space(3))) void*)l, 16, 0, 0);
}
__device__ __forceinline__ unsigned cvtpk(float lo, float hi) {
    unsigned r;
    asm("v_cvt_pk_bf16_f32 %0, %1, %2" : "=v"(r) : "v"(lo), "v"(hi));
    return r;
}

struct XPtrs { const float* p[4]; };

// ============ packed-K8 MFMA GEMM: C[m,n] = sum_k A[m,k]*Bpack[k,n] ============
enum { PM_QK = 0, PM_V = 1, PM_CAM = 2, PM_CONV = 3 };

template<int MODE>
__global__ __launch_bounds__(256)
void mfma_p_k(const u16* __restrict__ A, const u16* __restrict__ Bp,
              void* __restrict__ Cp,
              const float* __restrict__ b0, const float* __restrict__ b1,
              const float* __restrict__ gscale, XPtrs xs,
              int K, int lda, long aBatch, long bBatch, long cBatch, int sb0)
{
    const int n0 = blockIdx.x * 128, m0 = blockIdx.y * 128, z = blockIdx.z;
    const u16* Ab = A + (MODE == PM_CAM ? (size_t)(z & 1) * aBatch : (size_t)z * aBatch)
                      + (size_t)m0 * lda;
    const u16* Bb = Bp + (size_t)z * bBatch + (size_t)n0 * 8;

    __shared__ u16 As[4096];   // [kh][m][kl]
    __shared__ u16 Bs[4096];   // [kh][n][kl]

    const int t = threadIdx.x, lane = t & 63, w = t >> 6;
    const int mw = (w >> 1) * 64, nw = (w & 1) * 64;
    const int l15 = lane & 15, l4 = lane >> 4;

    f32x4 acc[4][4] = {};

    const u16* gaw = Ab + (size_t)lane * lda + w * 8;
    const u16* gbw = Bb + (size_t)w * (HW * 8) + (size_t)lane * 8;

    for (int kb = 0; kb < K; kb += 32) {
        gload16(gaw + kb,                    &As[w * 1024]);
        gload16(gaw + kb + (size_t)64 * lda, &As[w * 1024 + 512]);
        const u16* gb = gbw + (size_t)(kb >> 3) * (HW * 8);
        gload16(gb,       &Bs[w * 1024]);
        gload16(gb + 512, &Bs[w * 1024 + 512]);
        __syncthreads();

        bf16x8 af[4], bf[4];
        #pragma unroll
        for (int i = 0; i < 4; ++i) {
            af[i] = *(const bf16x8*)&As[l4 * 1024 + (mw + i * 16 + l15) * 8];
            bf[i] = *(const bf16x8*)&Bs[l4 * 1024 + (nw + i * 16 + l15) * 8];
        }
        #pragma unroll
        for (int mi = 0; mi < 4; ++mi)
            #pragma unroll
            for (int ni = 0; ni < 4; ++ni)
                acc[mi][ni] = __builtin_amdgcn_mfma_f32_16x16x32_bf16(af[mi], bf[ni], acc[mi][ni], 0, 0, 0);
        __syncthreads();
    }

    #pragma unroll
    for (int mi = 0; mi < 4; ++mi) {
        #pragma unroll
        for (int ni = 0; ni < 4; ++ni) {
            #pragma unroll
            for (int r = 0; r < 4; ++r) {
                const int row = m0 + mw + mi * 16 + l4 * 4 + r;
                const int col = n0 + nw + ni * 16 + l15;
                float v = acc[mi][ni][r];
                if constexpr (MODE == PM_QK) {
                    if (row < 64) {
                        v += (row < 32) ? b0[row] : b1[row - 32];
                        ((u16*)Cp)[(size_t)z * cBatch + (size_t)row * HW + col] = f2bf(v);
                    }
                } else if constexpr (MODE == PM_V) {
                    v += b0[row];
                    // packed V: Vp[(n>>3)*256 + c][n&7]  (contiguous 64KB kv-tiles)
                    ((u16*)Cp)[(size_t)z * cBatch
                               + (((size_t)(col >> 3) * 256 + row) << 3) + (col & 7)] = f2bf(v);
                } else if constexpr (MODE == PM_CAM) {
                    const float* xb = xs.p[z >> 1] + (size_t)(z & 1) * (256 * HW);
                    v = gscale[0] * v + 5.f * xb[(size_t)row * HW + col];
                    ((float*)Cp)[(size_t)z * cBatch + (size_t)row * HW + col] = v;
                } else { // PM_CONV
                    v += b0[row];
                    ((float*)Cp)[(size_t)(sb0 + z) * cBatch + (size_t)row * HW + col] = v;
                }
            }
        }
    }
}

// ============ flash v5: Yt[n][c] = gp * softmax(Q K^T) @ V^T ============
// QKt: [sb][4096][64] bf16 (cols 0-31 Q, 32-63 K). Vp: packed [kv>>3][256][8] bf16.
// 8 waves x 16 q-rows. Swapped QK: lane holds S[kv][qrow=l15]. Direct exp,
// in-register P via cvt_pk + ds_bpermute. Single 64KB V buffer, 2 barriers/iter:
//   barrier -> stage V(it) -> QK+softmax (global only, hides stage) -> barrier -> PV.
__global__ __launch_bounds__(512, 4)
void flash_k(const u16* __restrict__ QKt, const u16* __restrict__ Vp,
             float* __restrict__ Yt, const float* __restrict__ gscale)
{
    __shared__ u16 Vs[32768];   // 64KB V tile [g(16)][c(256)][8], linear

    const int sb = blockIdx.y;
    const int t = threadIdx.x, w = t >> 6, lane = t & 63;
    const int l15 = lane & 15, l4 = lane >> 4;
    const int q0 = blockIdx.x * 128 + w * 16;

    const u16* QKb = QKt + (size_t)sb * ((size_t)HW * 64);
    const u16* Vb  = Vp + (size_t)sb * ((size_t)256 * HW);
    float* Yb = Yt + (size_t)sb * ((size_t)HW * 256);

    // Q fragment (B operand): lane l15 = q-row q0+l15, k = l4*8..
    const bf16x8 aq = *(const bf16x8*)&QKb[(size_t)(q0 + l15) * 64 + l4 * 8];

    f32x4 acc[16] = {};
    float lrun = 0.f;
    const f32x4 zero4 = {0.f, 0.f, 0.f, 0.f};

    // bpermute byte-indices (constant per lane)
    const int idxA = (l15 + ((lane & 16) << 1)) << 2;   // src lane l15 + 32*(l4&1)
    const int idxB = idxA + (16 << 2);
    const bool jhi = (lane & 32) != 0;                  // j-select: l4>>1

    for (int it = 0; it < 32; ++it) {
        __syncthreads();   // all waves done reading Vs from previous iteration

        // stage V tile it -> Vs (async; QK+softmax below has no LDS dependency)
        const u16* vsrc = Vb + (size_t)it * 32768;
        #pragma unroll
        for (int i = 0; i < 8; ++i)
            gload16(vsrc + i * 4096 + t * 8, &Vs[i * 4096 + t * 8]);

        // QK^T swapped + direct-exp softmax, j-at-a-time (low VGPR)
        const int m0 = it * 128;
        unsigned pk[16];
        float tsum = 0.f;
        #pragma unroll
        for (int j = 0; j < 8; ++j) {
            const bf16x8 bk = *(const bf16x8*)&QKb[(size_t)(m0 + j * 16 + l15) * 64 + 32 + l4 * 8];
            const f32x4 sj = __builtin_amdgcn_mfma_f32_16x16x32_bf16(bk, aq, zero4, 0, 0, 0);
            const float e0 = __expf(sj[0]);
            const float e1 = __expf(sj[1]);
            const float e2 = __expf(sj[2]);
            const float e3 = __expf(sj[3]);
            tsum += (e0 + e1) + (e2 + e3);
            pk[2 * j]     = cvtpk(e0, e1);
            pk[2 * j + 1] = cvtpk(e2, e3);
        }
        tsum += __shfl_xor(tsum, 16);
        tsum += __shfl_xor(tsum, 32);
        lrun += tsum;

        __syncthreads();   // stage drained (compiler emits vmcnt(0) before barrier)

        // PV: assemble A-fragment in-register (bpermute) and accumulate
        #pragma unroll
        for (int ks = 0; ks < 4; ++ks) {
            u32x4 D;
            {
                const unsigned a0 = __builtin_amdgcn_ds_bpermute(idxA, (int)pk[4 * ks + 0]);
                const unsigned b0_ = __builtin_amdgcn_ds_bpermute(idxA, (int)pk[4 * ks + 2]);
                D[0] = jhi ? b0_ : a0;
                const unsigned a1 = __builtin_amdgcn_ds_bpermute(idxA, (int)pk[4 * ks + 1]);
                const unsigned b1_ = __builtin_amdgcn_ds_bpermute(idxA, (int)pk[4 * ks + 3]);
                D[1] = jhi ? b1_ : a1;
                const unsigned a2 = __builtin_amdgcn_ds_bpermute(idxB, (int)pk[4 * ks + 0]);
                const unsigned b2_ = __builtin_amdgcn_ds_bpermute(idxB, (int)pk[4 * ks + 2]);
                D[2] = jhi ? b2_ : a2;
                const unsigned a3 = __builtin_amdgcn_ds_bpermute(idxB, (int)pk[4 * ks + 1]);
                const unsigned b3_ = __builtin_amdgcn_ds_bpermute(idxB, (int)pk[4 * ks + 3]);
                D[3] = jhi ? b3_ : a3;
            }
            const bf16x8 ap = __builtin_bit_cast(bf16x8, D);
            #pragma unroll
            for (int ct = 0; ct < 16; ++ct) {
                const bf16x8 bv = *(const bf16x8*)&Vs[(4 * ks + l4) * 2048 + (ct * 16 + l15) * 8];
                acc[ct] = __builtin_amdgcn_mfma_f32_16x16x32_bf16(ap, bv, acc[ct], 0, 0, 0);
            }
        }
    }

    // epilogue: lrun lives at lane l15 = qrow; acc rows are l4*4+r -> bpermute
    const float gp = gscale[0];
    #pragma unroll
    for (int r = 0; r < 4; ++r) {
        const int srcl = ((lane & 48) | (l4 * 4 + r)) << 2;
        const float lr = __int_as_float(__builtin_amdgcn_ds_bpermute(srcl, __float_as_int(lrun)));
        const float sc = gp / lr;
        const int row = q0 + l4 * 4 + r;
        #pragma unroll
        for (int ct = 0; ct < 16; ++ct)
            Yb[(size_t)row * 256 + ct * 16 + l15] = acc[ct][r] * sc;
    }
}

// ============ X pack: X f32 [c][4096] -> Xp bf16 [c>>3][n][c&7] ============
__global__ __launch_bounds__(256)
void xpack_k(XPtrs xs, u16* __restrict__ Xp)
{
    __shared__ float tile[64][65];
    const int sb = blockIdx.z;
    const int n0 = blockIdx.x * 64, c0 = blockIdx.y * 64;
    const float* X = xs.p[sb >> 1] + (size_t)(sb & 1) * (256 * HW);
    u16* Xo = Xp + (size_t)sb * ((size_t)32 * HW * 8);
    const int t = threadIdx.x;
    {
        const int c = t >> 2, p = t & 3;
        const float4* s4 = (const float4*)&X[(size_t)(c0 + c) * HW + n0 + p * 16];
        #pragma unroll
        for (int i = 0; i < 4; ++i) {
            const float4 v = s4[i];
            tile[c][p * 16 + i * 4 + 0] = v.x;
            tile[c][p * 16 + i * 4 + 1] = v.y;
            tile[c][p * 16 + i * 4 + 2] = v.z;
            tile[c][p * 16 + i * 4 + 3] = v.w;
        }
    }
    __syncthreads();
    const int n = t >> 2;
    #pragma unroll
    for (int pp = 0; pp < 2; ++pp) {
        const int cg = (t & 3) * 2 + pp;
        u16 o[8];
        #pragma unroll
        for (int cl = 0; cl < 8; ++cl) o[cl] = f2bf(tile[cg * 8 + cl][n]);
        *(u16x8*)&Xo[(((size_t)(c0 >> 3) + cg) * HW + (n0 + n)) * 8] = *(u16x8*)o;
    }
}

// ============ bf16 transpose: QKc [64][4096] -> QKt [4096][64] per sb ============
__global__ __launch_bounds__(256)
void tqkT_k(const u16* __restrict__ src, u16* __restrict__ dst)
{
    __shared__ u16 tile[64][72];
    const int sb = blockIdx.y;
    const int n0 = blockIdx.x * 64;
    const u16* s = src + (size_t)sb * (64 * HW);
    u16* d = dst + (size_t)sb * (HW * 64);
    const int t = threadIdx.x;
    #pragma unroll
    for (int p = 0; p < 2; ++p) {
        const int c = (t >> 3) + p * 32, nn = (t & 7) * 8;
        const u16x8 v = *(const u16x8*)&s[(size_t)c * HW + n0 + nn];
        *(u16x8*)&tile[c][nn] = v;
    }
    __syncthreads();
    const int n = t >> 2, co = (t & 3) * 16;
    u16 o[16];
    #pragma unroll
    for (int j = 0; j < 16; ++j) o[j] = tile[co + j][n];
    *(u16x8*)&d[(size_t)(n0 + n) * 64 + co]     = *(u16x8*)&o[0];
    *(u16x8*)&d[(size_t)(n0 + n) * 64 + co + 8] = *(u16x8*)&o[8];
}

// ============ f32 split-K GRAM (precision-critical) ============
__global__ __launch_bounds__(256)
void gram_k(float* __restrict__ Gp, XPtrs xs)
{
    const int bx = blockIdx.x, by = blockIdx.y, bz = blockIdx.z;
    const int sbi = bz & 7;
    const int n0 = bx * 64, m0 = by * 64;
    const int t = threadIdx.x;
    const int tm = t >> 4, tn = t & 15;
    const float* xb = xs.p[sbi >> 1] + (size_t)(sbi & 1) * (256 * HW) + (bz >> 3) * 512;

    __shared__ float As[16][68];
    __shared__ float Bs[16][68];
    float acc[4][4] = {};

    for (int kb = 0; kb < 512; kb += 16) {
        {
            const int m = t >> 2, k0 = (t & 3) * 4;
            float4 v = *(const float4*)(xb + (size_t)(m0 + m) * HW + (kb + k0));
            As[k0 + 0][m] = v.x; As[k0 + 1][m] = v.y; As[k0 + 2][m] = v.z; As[k0 + 3][m] = v.w;
        }
        {
            const int n = t >> 2, k0 = (t & 3) * 4;
            float4 v = *(const float4*)(xb + (size_t)(n0 + n) * HW + (kb + k0));
            Bs[k0 + 0][n] = v.x; Bs[k0 + 1][n] = v.y; Bs[k0 + 2][n] = v.z; Bs[k0 + 3][n] = v.w;
        }
        __syncthreads();
        #pragma unroll
        for (int k = 0; k < 16; ++k) {
            const float4 a = *(const float4*)&As[k][tm * 4];
            const float4 b = *(const float4*)&Bs[k][tn * 4];
            acc[0][0] += a.x * b.x; acc[0][1] += a.x * b.y; acc[0][2] += a.x * b.z; acc[0][3] += a.x * b.w;
            acc[1][0] += a.y * b.x; acc[1][1] += a.y * b.y; acc[1][2] += a.y * b.z; acc[1][3] += a.y * b.w;
            acc[2][0] += a.z * b.x; acc[2][1] += a.z * b.y; acc[2][2] += a.z * b.z; acc[2][3] += a.z * b.w;
            acc[3][0] += a.w * b.x; acc[3][1] += a.w * b.y; acc[3][2] += a.w * b.z; acc[3][3] += a.w * b.w;
        }
        __syncthreads();
    }
    float* Cf = Gp + (size_t)bz * 65536;
    #pragma unroll
    for (int i = 0; i < 4; ++i) {
        const int m = m0 + tm * 4 + i;
        *(float4*)&Cf[(size_t)m * 256 + n0 + tn * 4] =
            make_float4(acc[i][0], acc[i][1], acc[i][2], acc[i][3]);
    }
}

__global__ __launch_bounds__(256)
void greduce_k(const float* __restrict__ Gp, float* __restrict__ G)
{
    const size_t i = (size_t)blockIdx.x * 256 + threadIdx.x;
    float s = 0.f;
    #pragma unroll
    for (int sp = 0; sp < 8; ++sp) s += Gp[(size_t)sp * 524288 + i];
    G[i] = s;
}

__global__ __launch_bounds__(256)
void cam_softmax_k(const float* __restrict__ G, float* __restrict__ attsum)
{
    __shared__ float rmn[4], rsm[4];
    const int c = blockIdx.x, b = blockIdx.y;
    const int d = threadIdx.x;
    float acc = 0.f;
    for (int s = 0; s < 4; ++s) {
        const float* row = G + (((size_t)(s * 2 + b)) * 256 + c) * 256;
        const float e = row[d];
        float mn = e;
        for (int o = 32; o; o >>= 1) mn = fminf(mn, __shfl_down(mn, o));
        if ((d & 63) == 0) rmn[d >> 6] = mn;
        __syncthreads();
        mn = fminf(fminf(rmn[0], rmn[1]), fminf(rmn[2], rmn[3]));
        const float ex = __expf(mn - e);
        float sm = ex;
        for (int o = 32; o; o >>= 1) sm += __shfl_down(sm, o);
        if ((d & 63) == 0) rsm[d >> 6] = sm;
        __syncthreads();
        sm = rsm[0] + rsm[1] + rsm[2] + rsm[3];
        acc += ex * (1.0f / sm);
        __syncthreads();
    }
    attsum[((size_t)b * 256 + c) * 256 + d] = acc;
}

// ============ transpose-add: Y[c][n] += Yt[n][c] ============
__global__ __launch_bounds__(256)
void transT_k(const float* __restrict__ Yt, float* __restrict__ Y)
{
    __shared__ float tile[64][65];
    const int sb = blockIdx.z;
    const int n0 = blockIdx.x * 64, c0 = blockIdx.y * 64;
    const float* src = Yt + (size_t)sb * ((size_t)HW * 256);
    float* dst = Y + (size_t)sb * ((size_t)256 * HW);
    const int t = threadIdx.x;
    {
        const int n = t >> 2, p = t & 3;
        const float4* s4 = (const float4*)&src[(size_t)(n0 + n) * 256 + c0 + p * 16];
        #pragma unroll
        for (int i = 0; i < 4; ++i) {
            const float4 v = s4[i];
            tile[n][p * 16 + i * 4 + 0] = v.x;
            tile[n][p * 16 + i * 4 + 1] = v.y;
            tile[n][p * 16 + i * 4 + 2] = v.z;
            tile[n][p * 16 + i * 4 + 3] = v.w;
        }
    }
    __syncthreads();
    const int c = t >> 2, p = t & 3;
    #pragma unroll
    for (int i = 0; i < 4; ++i) {
        float* dp = &dst[(size_t)(c0 + c) * HW + n0 + p * 16 + i * 4];
        float4 cur = *(float4*)dp;
        cur.x += tile[p * 16 + i * 4 + 0][c];
        cur.y += tile[p * 16 + i * 4 + 1][c];
        cur.z += tile[p * 16 + i * 4 + 2][c];
        cur.w += tile[p * 16 + i * 4 + 3][c];
        *(float4*)dp = cur;
    }
}

// ============ im2col (bf16, packed-K8): col[kg][n][kl] ============
__global__ __launch_bounds__(256)
void im2col_k(const float* __restrict__ Y, u16* __restrict__ col, int sb0)
{
    const int n = blockIdx.x * 256 + threadIdx.x;
    const int kg = blockIdx.y;
    const int sbl = blockIdx.z;
    const float* Yb = Y + (size_t)(sb0 + sbl) * ((size_t)256 * HW);
    const int h = n >> 6, wc = n & 63;
    u16 out[8];
    #pragma unroll
    for (int kl = 0; kl < 8; ++kl) {
        const int k = kg * 8 + kl;
        const int ic = k / 9, r = k - ic * 9;
        const int ih = h + r / 3 - 1, iw = wc + (r % 3) - 1;
        float v = 0.f;
        if (ih >= 0 && ih < 64 && iw >= 0 && iw < 64)
            v = Yb[(size_t)ic * HW + (ih << 6) + iw];
        out[kl] = f2bf(v);
    }
    *(u16x8*)&col[(((size_t)sbl * 288 + kg) * HW + n) * 8] = *(u16x8*)out;
}

// ============ flat f32 -> bf16 ============
__global__ __launch_bounds__(256)
void cvt_k(const float* __restrict__ s, u16* __restrict__ d)
{
    const size_t i = ((size_t)blockIdx.x * 256 + threadIdx.x) * 4;
    const float4 v = *(const float4*)&s[i];
    u16 o[4] = { f2bf(v.x), f2bf(v.y), f2bf(v.z), f2bf(v.w) };
    *(u16x4*)&d[i] = *(u16x4*)o;
}

extern "C" void kernel_launch(void* const* d_in, const int* in_sizes, int n_in,
                              void* d_out, int out_size, void* d_ws, size_t ws_size,
                              hipStream_t stream)
{
    XPtrs xs;
    xs.p[0] = (const float*)d_in[0];
    xs.p[1] = (const float*)d_in[1];
    xs.p[2] = (const float*)d_in[2];
    xs.p[3] = (const float*)d_in[3];
    const float* Wq = (const float*)d_in[4];
    const float* bq = (const float*)d_in[5];
    const float* Wk = (const float*)d_in[6];
    const float* bk = (const float*)d_in[7];
    const float* Wv = (const float*)d_in[8];
    const float* bv = (const float*)d_in[9];
    const float* gp = (const float*)d_in[10];
    const float* gc = (const float*)d_in[11];
    const float* Wd = (const float*)d_in[12];
    const float* bd = (const float*)d_in[13];

    char* base = (char*)d_ws;
    size_t off = 0;
    auto alloc = [&](size_t bytes) -> char* {
        char* p = base + off;
        off = (off + bytes + 255) & ~(size_t)255;
        return p;
    };

    // persistent through conv
    float* Y    = (float*)alloc((size_t)8 * 256 * HW * 4);      // 32 MB
    u16*   Wdh  = (u16*)  alloc((size_t)256 * 2304 * 2);        // 1.2 MB
    const size_t overlayStart = off;
    // dead before conv
    u16*   Xp   = (u16*)  alloc((size_t)8 * 32 * HW * 8 * 2);   // 16 MB
    u16*   Vp   = (u16*)  alloc((size_t)8 * 256 * HW * 2);      // 16 MB (packed kv-tiles)
    float* Yt   = (float*)alloc((size_t)8 * HW * 256 * 4);      // 32 MB
    u16*   QKc  = (u16*)  alloc((size_t)8 * 64 * HW * 2);       // 4 MB
    u16*   QKt  = (u16*)  alloc((size_t)8 * HW * 64 * 2);       // 4 MB
    float* Gp   = (float*)alloc((size_t)64 * 65536 * 4);        // 16 MB
    float* G    = (float*)alloc((size_t)8 * 65536 * 4);         // 2 MB
    float* att  = (float*)alloc((size_t)2 * 65536 * 4);         // 0.5 MB
    u16*   attH = (u16*)  alloc((size_t)2 * 65536 * 2);         // 0.25 MB
    u16*   Wqkh = (u16*)  alloc((size_t)128 * 256 * 2);         // 64 KB (rows 64-127 pad)
    u16*   Wvh  = (u16*)  alloc((size_t)256 * 256 * 2);         // 128 KB

    const size_t colPer = (size_t)288 * HW * 8 * 2;             // 18.9 MB / sb
    u16* colp = (u16*)(base + overlayStart);
    long nchunkL = (long)((ws_size - overlayStart) / colPer);
    const int nchunk = (int)(nchunkL > 8 ? 8 : (nchunkL < 1 ? 1 : nchunkL));

    dim3 T(256);

    // packs + weight converts
    xpack_k<<<dim3(64, 4, 8), T, 0, stream>>>(xs, Xp);
    cvt_k<<<dim3(8),   T, 0, stream>>>(Wq, Wqkh);
    cvt_k<<<dim3(8),   T, 0, stream>>>(Wk, Wqkh + 32 * 256);
    cvt_k<<<dim3(64),  T, 0, stream>>>(Wv, Wvh);
    cvt_k<<<dim3(576), T, 0, stream>>>(Wd, Wdh);

    // CAM attention matrix (f32 path)
    gram_k<<<dim3(4, 4, 64), T, 0, stream>>>(Gp, xs);
    greduce_k<<<dim3(2048), T, 0, stream>>>(Gp, G);
    cam_softmax_k<<<dim3(256, 2), T, 0, stream>>>(G, att);
    cvt_k<<<dim3(128), T, 0, stream>>>(att, attH);

    // projections (packed-B MFMA)
    mfma_p_k<PM_QK><<<dim3(32, 1, 8), T, 0, stream>>>(Wqkh, Xp, QKc, bq, bk, nullptr, xs,
                                                      256, 256, 0, (long)32 * HW * 8, (long)64 * HW, 0);
    tqkT_k<<<dim3(64, 8), T, 0, stream>>>(QKc, QKt);
    mfma_p_k<PM_V><<<dim3(32, 2, 8), T, 0, stream>>>(Wvh, Xp, Vp, bv, nullptr, nullptr, xs,
                                                     256, 256, 0, (long)32 * HW * 8, (long)256 * HW, 0);

    // fused flash PAM (swapped-QK, in-register P, single-buffer V)
    flash_k<<<dim3(32, 8), dim3(512), 0, stream>>>(QKt, Vp, Yt, gp);

    // CAM apply: Y = gc * attsum[b] @ X + 5X   (packed-B MFMA)
    mfma_p_k<PM_CAM><<<dim3(32, 2, 8), T, 0, stream>>>(attH, Xp, Y, nullptr, nullptr, gc, xs,
                                                       256, 256, 65536, (long)32 * HW * 8, (long)256 * HW, 0);

    // Y += Yt^T  (PAM contribution)
    transT_k<<<dim3(64, 4, 8), T, 0, stream>>>(Yt, Y);

    // 3x3 conv: packed im2col + MFMA GEMM, chunked by ws capacity
    for (int c0 = 0; c0 < 8; c0 += nchunk) {
        const int cs = (8 - c0 < nchunk) ? (8 - c0) : nchunk;
        im2col_k<<<dim3(16, 288, cs), T, 0, stream>>>(Y, colp, c0);
        mfma_p_k<PM_CONV><<<dim3(32, 2, cs), T, 0, stream>>>(Wdh, colp, d_out, bd, nullptr, nullptr, xs,
                                                             2304, 2304, 0, (long)288 * HW * 8, (long)256 * HW, c0);
    }
}